// Round 1
// baseline (308.467 us; speedup 1.0000x reference)
//
#include <hip/hip_runtime.h>

// Problem constants (from reference)
constexpr int T   = 5;
constexpr int BS  = 32;
constexpr int C   = 64;
constexpr int H   = 64;
constexpr int W   = 64;
constexpr int HW  = H * W;        // 4096
constexpr int CHW = C * HW;       // 262144
constexpr int N   = T * BS;       // 160
constexpr float TAU = 0.5f;
// gamma computed in double then cast to f32, matching jax weak-type promotion
constexpr float GAMMA = (float)(0.1 / 49.0);

// ---------------------------------------------------------------------------
// Kernel 1: block_mask[n,h,w] = 1 - maxpool7x7_SAME( mask_noise[n,h,w] < GAMMA )
// One block per n-plane. Separable max: row-window max into LDS, then
// column-window max. 2 x 16 KB LDS. Column access rowmax[hh][w] is
// 2-way bank aliasing (free on gfx950).
// ---------------------------------------------------------------------------
__global__ void __launch_bounds__(256)
block_mask_kernel(const float* __restrict__ mask_noise,
                  float* __restrict__ block_mask) {
    __shared__ float bin[H][W];
    __shared__ float rowmax[H][W];
    const int n = blockIdx.x;
    const float* mn = mask_noise + (size_t)n * HW;

    for (int i = threadIdx.x; i < HW; i += blockDim.x) {
        bin[i >> 6][i & 63] = (mn[i] < GAMMA) ? 1.0f : 0.0f;
    }
    __syncthreads();

    // row-wise max over w in [w-3, w+3] clamped
    for (int i = threadIdx.x; i < HW; i += blockDim.x) {
        const int h = i >> 6, w = i & 63;
        const int w0 = max(w - 3, 0), w1 = min(w + 3, W - 1);
        float m = 0.0f;
        for (int ww = w0; ww <= w1; ++ww) m = fmaxf(m, bin[h][ww]);
        rowmax[h][w] = m;
    }
    __syncthreads();

    // col-wise max over h in [h-3, h+3] clamped; write 1 - pooled
    for (int i = threadIdx.x; i < HW; i += blockDim.x) {
        const int h = i >> 6, w = i & 63;
        const int h0 = max(h - 3, 0), h1 = min(h + 3, H - 1);
        float m = 0.0f;
        for (int hh = h0; hh <= h1; ++hh) m = fmaxf(m, rowmax[hh][w]);
        block_mask[(size_t)n * HW + i] = 1.0f - m;
    }
}

// ---------------------------------------------------------------------------
// Kernel 2: LIF scan. One thread owns a float4 of (b,c,h,w) cells; u carried
// in registers across the fully-unrolled T=5 loop. Coalesced float4 loads of
// x and block_mask; vth is a per-(t,b) scalar (uniform within a block except
// at plane boundaries -> L1 broadcast).
//
// Numerics match the fp32 reference exactly:
//   0.5f*u is exact; (u - vt >= 0) <=> (u >= vt) in IEEE fp32.
// ---------------------------------------------------------------------------
__global__ void __launch_bounds__(256)
lif_kernel(const float* __restrict__ x,
           const float* __restrict__ vth,
           const float* __restrict__ block_mask,
           float* __restrict__ out) {
    const int tid = blockIdx.x * blockDim.x + threadIdx.x;  // vec4 index
    const int e   = tid * 4;                                // element index in [0, BS*CHW)
    const int b   = e / CHW;
    const int rem = e - b * CHW;
    const int c   = rem / HW;
    const int hw  = rem - c * HW;

    float4 u = make_float4(0.0f, 0.0f, 0.0f, 0.0f);

#pragma unroll
    for (int t = 0; t < T; ++t) {
        const int nb = t * BS + b;
        const float4 x4 = *(const float4*)(x + (size_t)nb * CHW + (size_t)c * HW + hw);
        const float4 m4 = *(const float4*)(block_mask + (size_t)nb * HW + hw);
        const float  vt = vth[nb];

        float4 o4;
        // lane x
        u.x = TAU * u.x + x4.x;
        if (u.x >= vt) { o4.x = m4.x; u.x -= vt; } else { o4.x = 0.0f; }
        // lane y
        u.y = TAU * u.y + x4.y;
        if (u.y >= vt) { o4.y = m4.y; u.y -= vt; } else { o4.y = 0.0f; }
        // lane z
        u.z = TAU * u.z + x4.z;
        if (u.z >= vt) { o4.z = m4.z; u.z -= vt; } else { o4.z = 0.0f; }
        // lane w
        u.w = TAU * u.w + x4.w;
        if (u.w >= vt) { o4.w = m4.w; u.w -= vt; } else { o4.w = 0.0f; }

        *(float4*)(out + (size_t)nb * CHW + (size_t)c * HW + hw) = o4;
    }
}

extern "C" void kernel_launch(void* const* d_in, const int* in_sizes, int n_in,
                              void* d_out, int out_size, void* d_ws, size_t ws_size,
                              hipStream_t stream) {
    const float* x          = (const float*)d_in[0];   // [N, C, H, W]
    const float* vth        = (const float*)d_in[1];   // [N]
    const float* mask_noise = (const float*)d_in[2];   // [N, H, W]
    float* out = (float*)d_out;                        // [N, C, H, W]
    float* bm  = (float*)d_ws;                         // [N, H, W] scratch (2.62 MB)

    block_mask_kernel<<<N, 256, 0, stream>>>(mask_noise, bm);

    const int nvec   = (BS * CHW) / 4;    // 2,097,152 float4 threads
    const int blocks = nvec / 256;        // 8192 blocks
    lif_kernel<<<blocks, 256, 0, stream>>>(x, vth, bm, out);
}

// Round 3
// 289.718 us; speedup vs baseline: 1.0647x; 1.0647x over previous
//
#include <hip/hip_runtime.h>

// Problem constants (from reference)
constexpr int T   = 5;
constexpr int BS  = 32;
constexpr int C   = 64;
constexpr int H   = 64;
constexpr int W   = 64;
constexpr int HW  = H * W;        // 4096
constexpr int CHW = C * HW;       // 262144
constexpr int N   = T * BS;       // 160
constexpr float TAU = 0.5f;
// gamma computed in double then cast to f32, matching jax weak-type promotion
constexpr float GAMMA = (float)(0.1 / 49.0);

// native vector type usable with __builtin_nontemporal_{load,store}
typedef float v4f __attribute__((ext_vector_type(4)));

// ---------------------------------------------------------------------------
// Kernel 1: block_mask[n,h,w] = 1 - maxpool7x7_SAME( mask_noise[n,h,w] < GAMMA )
// 4 row-chunks per plane (16 output rows each, 3-row halo) -> 640 blocks so
// the whole GPU participates. Separable max: row-window max in LDS, then
// column-window max over the halo'd chunk.
// ---------------------------------------------------------------------------
__global__ void __launch_bounds__(256)
block_mask_kernel(const float* __restrict__ mask_noise,
                  float* __restrict__ block_mask) {
    __shared__ float bin[22][W];
    __shared__ float rowmax[22][W];
    const int n     = blockIdx.x >> 2;
    const int chunk = blockIdx.x & 3;
    const int r0    = chunk * 16;                 // first output row
    const int gh0   = max(r0 - 3, 0);             // first input row (global)
    const int gh1   = min(r0 + 15 + 3, H - 1);    // last input row (global)
    const int nrows = gh1 - gh0 + 1;              // <= 22

    const float* mn = mask_noise + (size_t)n * HW + (size_t)gh0 * W;

    // binarize halo'd rows into LDS
    for (int i = threadIdx.x; i < nrows * W; i += blockDim.x) {
        bin[i >> 6][i & 63] = (mn[i] < GAMMA) ? 1.0f : 0.0f;
    }
    __syncthreads();

    // row-wise max over w-window [w-3, w+3] clamped
    for (int i = threadIdx.x; i < nrows * W; i += blockDim.x) {
        const int h = i >> 6, w = i & 63;
        const int w0 = max(w - 3, 0), w1 = min(w + 3, W - 1);
        float m = 0.0f;
        for (int ww = w0; ww <= w1; ++ww) m = fmaxf(m, bin[h][ww]);
        rowmax[h][w] = m;
    }
    __syncthreads();

    // col-wise max over h-window, write 1 - pooled for the 16 output rows
    for (int i = threadIdx.x; i < 16 * W; i += blockDim.x) {
        const int ho = r0 + (i >> 6), w = i & 63;
        const int h0 = max(ho - 3, 0) - gh0, h1 = min(ho + 3, H - 1) - gh0;
        float m = 0.0f;
        for (int hh = h0; hh <= h1; ++hh) m = fmaxf(m, rowmax[hh][w]);
        block_mask[(size_t)n * HW + (size_t)ho * W + w] = 1.0f - m;
    }
}

// ---------------------------------------------------------------------------
// Kernel 2: LIF scan. One thread owns 4 (b,c,h,w) cells; u carried in
// registers across the fully-unrolled T=5 loop. x is streamed once and out
// written once -> non-temporal, keeping the 2.6 MB block_mask (reused 64x per
// plane) resident in L2. vth is a per-(t,b) scalar (L1 broadcast).
//
// Numerics match the fp32 reference exactly:
//   0.5f*u is exact; (u - vt >= 0) <=> (u >= vt) in IEEE fp32.
// ---------------------------------------------------------------------------
__global__ void __launch_bounds__(256)
lif_kernel(const float* __restrict__ x,
           const float* __restrict__ vth,
           const float* __restrict__ block_mask,
           float* __restrict__ out) {
    const int tid = blockIdx.x * blockDim.x + threadIdx.x;  // vec4 index
    const int e   = tid * 4;                                // element index in [0, BS*CHW)
    const int b   = e / CHW;
    const int rem = e - b * CHW;
    const int c   = rem / HW;
    const int hw  = rem - c * HW;

    v4f u = (v4f)(0.0f);

#pragma unroll
    for (int t = 0; t < T; ++t) {
        const int nb = t * BS + b;
        const v4f x4 = __builtin_nontemporal_load(
            (const v4f*)(x + (size_t)nb * CHW + (size_t)c * HW + hw));
        const v4f m4 = *(const v4f*)(block_mask + (size_t)nb * HW + hw);
        const float vt = vth[nb];

        v4f o4;
        u.x = TAU * u.x + x4.x;
        if (u.x >= vt) { o4.x = m4.x; u.x -= vt; } else { o4.x = 0.0f; }
        u.y = TAU * u.y + x4.y;
        if (u.y >= vt) { o4.y = m4.y; u.y -= vt; } else { o4.y = 0.0f; }
        u.z = TAU * u.z + x4.z;
        if (u.z >= vt) { o4.z = m4.z; u.z -= vt; } else { o4.z = 0.0f; }
        u.w = TAU * u.w + x4.w;
        if (u.w >= vt) { o4.w = m4.w; u.w -= vt; } else { o4.w = 0.0f; }

        __builtin_nontemporal_store(o4,
            (v4f*)(out + (size_t)nb * CHW + (size_t)c * HW + hw));
    }
}

extern "C" void kernel_launch(void* const* d_in, const int* in_sizes, int n_in,
                              void* d_out, int out_size, void* d_ws, size_t ws_size,
                              hipStream_t stream) {
    const float* x          = (const float*)d_in[0];   // [N, C, H, W]
    const float* vth        = (const float*)d_in[1];   // [N]
    const float* mask_noise = (const float*)d_in[2];   // [N, H, W]
    float* out = (float*)d_out;                        // [N, C, H, W]
    float* bm  = (float*)d_ws;                         // [N, H, W] scratch (2.62 MB)

    block_mask_kernel<<<N * 4, 256, 0, stream>>>(mask_noise, bm);

    const int nvec   = (BS * CHW) / 4;    // 2,097,152 float4 threads
    const int blocks = nvec / 256;        // 8192 blocks
    lif_kernel<<<blocks, 256, 0, stream>>>(x, vth, bm, out);
}